// Round 10
// baseline (222.190 us; speedup 1.0000x reference)
//
#include <hip/hip_runtime.h>
#include <math.h>

// ---------------------------------------------------------------------------
// Deep4Net via bf16 MFMA 32x32x16 (fp32 accum), 6 dispatches:
//  k_prep2   : fuse conv1+conv2 weights, transpose+pad all weights to bf16
//  k_conv12m : conv12 -> p1T[b][330][32] bf16 (2816 blocks, LDS-staged)
//  k_cgemm x3: conv3/conv4/conv5 as flat im2col-view GEMMs. Column dimension
//              is (b, u) flattened (N = 256*UPB, divisible by 3); B-fragment
//              for K-slice (k, i..i+7) is the contiguous 16B at
//              xT[b][u+k][i] -- no im2col materialization, no LDS, no
//              barriers. n-tiles stride 30 (width 32) so pool-of-3 triples
//              are lane-adjacent -> in-register shuffle pooling.
//  k_head    : routed per-sample linear from f32 feats.
// C/D layout (32x32): col = lane&31, row = (reg&3)+8*(reg>>2)+4*(lane>>5).
// o/i zero-padding in weights+bias makes padded output rows exactly 0, so
// padded K-lanes of the next layer contribute nothing (self-consistent).
//
// Workspace: float region then short(bf16) region.
#define F_BC   0         // 32   combined bias (padded)
#define F_B2   32        // 64
#define F_B3   96        // 128
#define F_B4   224       // 224
#define F_P4   448       // 256*1400 f32 features
#define SHORT_BASE 717696
#define WK12   0         // [10][32][32]
#define WK3    10240     // [10][64][32]
#define WK4    30720     // [10][128][64]
#define WK5    112640    // [10][224][128]
#define P1T    399360    // [256][330][32]
#define P2T    3102720   // [256][107][64]
#define P3T    4855808   // [256][32][128]
// ---------------------------------------------------------------------------

typedef __attribute__((ext_vector_type(8))) short short8;
typedef __attribute__((ext_vector_type(16))) float f32x16;

__device__ __forceinline__ short f2bf(float f) {
    union { float f; unsigned u; } v; v.f = f;
    unsigned r = v.u + 0x7FFF + ((v.u >> 16) & 1);
    return (short)(r >> 16);
}

// ---- K0: weight prep ------------------------------------------------------
__global__ __launch_bounds__(256) void k_prep2(
    const float* __restrict__ wt, const float* __restrict__ bt,
    const float* __restrict__ wsp, const float* __restrict__ bsp,
    const float* __restrict__ w2, const float* __restrict__ b2,
    const float* __restrict__ w3, const float* __restrict__ b3,
    const float* __restrict__ w4, const float* __restrict__ b4,
    float* __restrict__ wsf, short* __restrict__ wss) {
    int idx = blockIdx.x * 256 + threadIdx.x;
    if (idx < 448) {                           // padded biases (f32)
        float v = 0.f;
        if (idx < 32) {
            int o = idx;
            if (o < 25) {
                v = bsp[o];
                for (int i = 0; i < 25; ++i) {
                    float rs = 0.f;
                    for (int c = 0; c < 22; ++c) rs += wsp[(o * 25 + i) * 22 + c];
                    v += bt[i] * rs;
                }
            }
        } else if (idx < 96)  { int o = idx - 32;  v = (o < 50)  ? b2[o] : 0.f; }
        else if (idx < 224)   { int o = idx - 96;  v = (o < 100) ? b3[o] : 0.f; }
        else                  { int o = idx - 224; v = (o < 200) ? b4[o] : 0.f; }
        wsf[idx] = v;
        return;
    }
    int j = idx - 448;
    if (j < 10240) {                           // wk12 [k][32][32] (combined)
        int k = j / 1024, o = (j / 32) % 32, i = j % 32;
        float v = 0.f;
        if (o < 25 && i < 22)
            for (int q = 0; q < 25; ++q) v += wt[q * 10 + k] * wsp[(o * 25 + q) * 22 + i];
        wss[WK12 + j] = f2bf(v);
        return;
    }
    j -= 10240;
    if (j < 20480) {                           // wk3 [k][64][32]
        int k = j / 2048, o = (j / 32) % 64, i = j % 32;
        float v = (o < 50 && i < 25) ? w2[(o * 25 + i) * 10 + k] : 0.f;
        wss[WK3 + j] = f2bf(v);
        return;
    }
    j -= 20480;
    if (j < 81920) {                           // wk4 [k][128][64]
        int k = j / 8192, o = (j / 64) % 128, i = j % 64;
        float v = (o < 100 && i < 50) ? w3[(o * 50 + i) * 10 + k] : 0.f;
        wss[WK4 + j] = f2bf(v);
        return;
    }
    j -= 81920;
    if (j < 286720) {                          // wk5 [k][224][128]
        int k = j / 28672, o = (j / 128) % 224, i = j % 128;
        float v = (o < 200 && i < 100) ? w4[(o * 100 + i) * 10 + k] : 0.f;
        wss[WK5 + j] = f2bf(v);
    }
}

// ---- K1: conv12 via 32x32x16 MFMA -> p1T[b][330][32] bf16 -----------------
__global__ __launch_bounds__(192) void k_conv12m(
    const short* __restrict__ wk, const float* __restrict__ bias,
    const float* __restrict__ xf32, short* __restrict__ outT) {
    constexpr int NCHUNK = 96, ROWS = NCHUNK + 9, XSTR = 36, SSTR = 33;
    __shared__ short xs[ROWS * XSTR];
    __shared__ float sc[NCHUNK * SSTR];

    int idx = blockIdx.x;
    int b = idx % 256;
    int nc = idx / 256;            // 0..10
    int t0 = nc * NCHUNK;
    int tid = threadIdx.x;

    const float* xb = xf32 + b * 22000;
    for (int i = tid; i < 32 * ROWS; i += 192) {
        int c = i / ROWS, r = i - c * ROWS;
        short v = 0;
        if (c < 22) {
            int t = t0 + r; if (t > 999) t = 999;
            v = f2bf(xb[c * 1000 + t]);
        }
        xs[r * XSTR + c] = v;
    }
    __syncthreads();

    int w = tid >> 6, lane = tid & 63, l31 = lane & 31, half = lane >> 5;
    int nt = w;                    // 3 n-tiles of 32

    f32x16 acc = {};
    const short* wbase = wk + (size_t)l31 * 32 + half * 8;
#pragma unroll 2
    for (int k = 0; k < 10; ++k) {
#pragma unroll
        for (int kb = 0; kb < 2; ++kb) {
            short8 a = *(const short8*)(wbase + (size_t)k * 32 * 32 + kb * 16);
            short8 bf = *(const short8*)(xs + (nt * 32 + l31 + k) * XSTR +
                                         kb * 16 + half * 8);
            acc = __builtin_amdgcn_mfma_f32_32x32x16_bf16(a, bf, acc, 0, 0, 0);
        }
    }
    {
        float* scl = sc + (nt * 32 + l31) * SSTR + 4 * half;
#pragma unroll
        for (int reg = 0; reg < 16; ++reg)
            scl[(reg & 3) + 8 * (reg >> 2)] = acc[reg];
    }
    __syncthreads();

    int pc0 = nc * 32;
    for (int i = tid; i < 32 * 32; i += 192) {
        int tp = i >> 5, ol = i & 31;
        if (pc0 + tp < 330) {
            float s0 = sc[(tp * 3 + 0) * SSTR + ol];
            float s1 = sc[(tp * 3 + 1) * SSTR + ol];
            float s2 = sc[(tp * 3 + 2) * SSTR + ol];
            float m = fmaxf(fmaxf(s0, s1), s2) + bias[ol];
            float e = m > 0.f ? m : __expf(m) - 1.f;
            outT[(size_t)b * 330 * 32 + (size_t)(pc0 + tp) * 32 + ol] = f2bf(e);
        }
    }
}

// ---- K2-4: flat im2col-view conv GEMM, no LDS, no barriers ----------------
// wave = one task (mt, nt); columns c = nt*30 + l31, c = b*UPB + u.
// B-frag: xT[b][u+k][kb*16 + half*8 ..+7]; A-frag: wk[k][mt*32+l31][...].
template<int OPAD, int IPAD, int MT, int UPB, int TIN, int TPOUT, bool F32OUT>
__global__ __launch_bounds__(256) void k_cgemm(
    const short* __restrict__ wk, const float* __restrict__ bias,
    const short* __restrict__ xT, short* __restrict__ outT,
    float* __restrict__ feats, int NT, int N) {
    constexpr int KB = IPAD / 16;
    int tid = threadIdx.x;
    int w = tid >> 6, lane = tid & 63, l31 = lane & 31, half = lane >> 5;
    int task = blockIdx.x * 4 + w;
    int mt = task / NT, nt = task - mt * NT;
    int c = nt * 30 + l31;
    int cc = c < N ? c : N - 1;
    int b = cc / UPB;
    int u = cc - b * UPB;

    f32x16 acc0 = {}, acc1 = {};
    const short* abase = wk + (size_t)(mt * 32 + l31) * IPAD + half * 8;
    const short* bbase = xT + ((size_t)b * TIN + u) * IPAD + half * 8;
#pragma unroll 2
    for (int k = 0; k < 10; ++k) {
        const short* ap = abase + (size_t)k * OPAD * IPAD;
        const short* bp = bbase + k * IPAD;
#pragma unroll
        for (int kb = 0; kb < KB; kb += 2) {
            acc0 = __builtin_amdgcn_mfma_f32_32x32x16_bf16(
                *(const short8*)(ap + kb * 16), *(const short8*)(bp + kb * 16),
                acc0, 0, 0, 0);
            acc1 = __builtin_amdgcn_mfma_f32_32x32x16_bf16(
                *(const short8*)(ap + kb * 16 + 16), *(const short8*)(bp + kb * 16 + 16),
                acc1, 0, 0, 0);
        }
    }

    bool actL = ((l31 % 3) == 0) && (l31 < 30) && (c < N);
    int tp = u / 3;                     // u % 3 == 0 whenever actL
#pragma unroll
    for (int q = 0; q < 4; ++q) {
        float ev[4];
#pragma unroll
        for (int rr = 0; rr < 4; ++rr) {
            int reg = q * 4 + rr;
            float v = acc0[reg] + acc1[reg];
            float v1 = __shfl_down(v, 1);
            float v2 = __shfl_down(v, 2);
            float m = fmaxf(fmaxf(v, v1), v2) +
                      bias[mt * 32 + q * 8 + 4 * half + rr];
            ev[rr] = m > 0.f ? m : __expf(m) - 1.f;
        }
        if constexpr (F32OUT) {
            if (actL) {
                int ogb = mt * 32 + q * 8 + 4 * half;
#pragma unroll
                for (int rr = 0; rr < 4; ++rr)
                    if (ogb + rr < 200)
                        feats[(size_t)b * 1400 + (ogb + rr) * 7 + tp] = ev[rr];
            }
        } else {
            if (actL) {
                short4 hv;
                hv.x = f2bf(ev[0]); hv.y = f2bf(ev[1]);
                hv.z = f2bf(ev[2]); hv.w = f2bf(ev[3]);
                *(short4*)(outT + ((size_t)b * TPOUT + tp) * OPAD +
                           mt * 32 + q * 8 + 4 * half) = hv;
            }
        }
    }
}

// ---- K5: routed head, one wave per output ---------------------------------
__global__ __launch_bounds__(256) void k_head(const float* __restrict__ hW,
                                              const float* __restrict__ hB,
                                              const int* __restrict__ sid,
                                              const float* __restrict__ p4,
                                              float* __restrict__ out) {
    int b = blockIdx.x;
    int tid = threadIdx.x;
    int wave = tid >> 6, lane = tid & 63;
    int sidb = sid[b];
    const float4* wrow = reinterpret_cast<const float4*>(hW + (size_t)(sidb * 4 + wave) * 1400);
    const float4* feat = reinterpret_cast<const float4*>(p4 + (size_t)b * 1400);
    float acc = 0.f;
    for (int f = lane; f < 350; f += 64) {
        float4 a = wrow[f], c = feat[f];
        acc += a.x * c.x + a.y * c.y + a.z * c.z + a.w * c.w;
    }
#pragma unroll
    for (int off = 32; off; off >>= 1) acc += __shfl_down(acc, off);
    if (lane == 0) out[b * 4 + wave] = acc + hB[sidb * 4 + wave];
}

extern "C" void kernel_launch(void* const* d_in, const int* in_sizes, int n_in,
                              void* d_out, int out_size, void* d_ws, size_t ws_size,
                              hipStream_t stream) {
    const float* x   = (const float*)d_in[0];
    const int*   sid = (const int*)d_in[1];
    const float* wt  = (const float*)d_in[2];
    const float* bt  = (const float*)d_in[3];
    const float* wsp = (const float*)d_in[4];
    const float* bsp = (const float*)d_in[5];
    const float* w2  = (const float*)d_in[6];
    const float* b2  = (const float*)d_in[7];
    const float* w3  = (const float*)d_in[8];
    const float* b3  = (const float*)d_in[9];
    const float* w4  = (const float*)d_in[10];
    const float* b4  = (const float*)d_in[11];
    const float* hW  = (const float*)d_in[12];
    const float* hB  = (const float*)d_in[13];
    float* out = (float*)d_out;
    float* wsf = (float*)d_ws;
    short* wss = (short*)d_ws + SHORT_BASE;

    k_prep2<<<1562, 256, 0, stream>>>(wt, bt, wsp, bsp, w2, b2, w3, b3, w4, b4,
                                      wsf, wss);
    k_conv12m<<<256 * 11, 192, 0, stream>>>(wss + WK12, wsf + F_BC, x, wss + P1T);
    // conv3: N = 256*321 = 82176, NT = 2740, tasks = 2*2740 = 5480
    k_cgemm<64, 32, 2, 321, 330, 107, false><<<1370, 256, 0, stream>>>(
        wss + WK3, wsf + F_B2, wss + P1T, wss + P2T, nullptr, 2740, 82176);
    // conv4: N = 256*96 = 24576, NT = 820, tasks = 4*820 = 3280
    k_cgemm<128, 64, 4, 96, 107, 32, false><<<820, 256, 0, stream>>>(
        wss + WK4, wsf + F_B3, wss + P2T, wss + P3T, nullptr, 820, 24576);
    // conv5: N = 256*21 = 5376, NT = 180, tasks = 7*180 = 1260
    k_cgemm<224, 128, 7, 21, 32, 7, true><<<315, 256, 0, stream>>>(
        wss + WK5, wsf + F_B4, wss + P3T, nullptr, wsf + F_P4, 180, 5376);
    k_head<<<256, 256, 0, stream>>>(hW, hB, sid, wsf + F_P4, out);
}

// Round 12
// 192.774 us; speedup vs baseline: 1.1526x; 1.1526x over previous
//
#include <hip/hip_runtime.h>
#include <math.h>

// ---------------------------------------------------------------------------
// Deep4Net via bf16 MFMA 32x32x16 (fp32 accum), 5 dispatches:
//  k_prep2 : fuse conv1+conv2 weights, transpose+pad all weights to bf16
//  k_conv12/k_conv3/k_conv4/k_conv5h : stage-split conv layers. Each block
//    stages one x-window in LDS (bf16 time-major, row pad +4 shorts), waves
//    compute overlapping 32-wide n-tiles at stride 30 so every pool-of-3 is
//    lane-adjacent in the C fragment -> in-register shuffle pooling (no LDS
//    epilogue scratch, ONE barrier per block). conv3/conv4 waves carry 2
//    m-tiles (2 accs share each B-frag -> half the ds_read per MFMA).
//    conv5 fuses the routed head (feats stay in LDS).
// Frag maps (32x32x16, verified R8-R10):
//  A: wk[k][o=mt*32+l31][i=kb*16+half*8 ..+7]; B: xs[u=nt*30+l31+k][same i]
//  C/D: col(u)=l31, row(o)=(reg&3)+8*(reg>>2)+4*half
// R12 fix: conv4 m-pair indexing (was covering 256 rows -> OOB writes);
// grid 256, pair = w&1 covering exactly 128 padded rows.
//
// Workspace: float region then short(bf16) region.
#define F_BC   0
#define F_B2   32
#define F_B3   96
#define F_B4   224
#define SHORT_BASE 717696
#define WK12   0         // [10][32][32]
#define WK3    10240     // [10][64][32]
#define WK4    30720     // [10][128][64]
#define WK5    112640    // [10][224][128]
#define P1T    399360    // [256][330][32]
#define P2T    3102720   // [256][107][64]
#define P3T    4855808   // [256][32][128]
// ---------------------------------------------------------------------------

typedef __attribute__((ext_vector_type(8))) short short8;
typedef __attribute__((ext_vector_type(16))) float f32x16;

__device__ __forceinline__ short f2bf(float f) {
    union { float f; unsigned u; } v; v.f = f;
    unsigned r = v.u + 0x7FFF + ((v.u >> 16) & 1);
    return (short)(r >> 16);
}

// ---- K0: weight prep ------------------------------------------------------
__global__ __launch_bounds__(256) void k_prep2(
    const float* __restrict__ wt, const float* __restrict__ bt,
    const float* __restrict__ wsp, const float* __restrict__ bsp,
    const float* __restrict__ w2, const float* __restrict__ b2,
    const float* __restrict__ w3, const float* __restrict__ b3,
    const float* __restrict__ w4, const float* __restrict__ b4,
    float* __restrict__ wsf, short* __restrict__ wss) {
    int idx = blockIdx.x * 256 + threadIdx.x;
    if (idx < 448) {
        float v = 0.f;
        if (idx < 32) {
            int o = idx;
            if (o < 25) {
                v = bsp[o];
                for (int i = 0; i < 25; ++i) {
                    float rs = 0.f;
                    for (int c = 0; c < 22; ++c) rs += wsp[(o * 25 + i) * 22 + c];
                    v += bt[i] * rs;
                }
            }
        } else if (idx < 96)  { int o = idx - 32;  v = (o < 50)  ? b2[o] : 0.f; }
        else if (idx < 224)   { int o = idx - 96;  v = (o < 100) ? b3[o] : 0.f; }
        else                  { int o = idx - 224; v = (o < 200) ? b4[o] : 0.f; }
        wsf[idx] = v;
        return;
    }
    int j = idx - 448;
    if (j < 10240) {                           // wk12 [k][32][32]
        int k = j / 1024, o = (j / 32) % 32, i = j % 32;
        float v = 0.f;
        if (o < 25 && i < 22)
            for (int q = 0; q < 25; ++q) v += wt[q * 10 + k] * wsp[(o * 25 + q) * 22 + i];
        wss[WK12 + j] = f2bf(v);
        return;
    }
    j -= 10240;
    if (j < 20480) {                           // wk3 [k][64][32]
        int k = j / 2048, o = (j / 32) % 64, i = j % 32;
        float v = (o < 50 && i < 25) ? w2[(o * 25 + i) * 10 + k] : 0.f;
        wss[WK3 + j] = f2bf(v);
        return;
    }
    j -= 20480;
    if (j < 81920) {                           // wk4 [k][128][64]
        int k = j / 8192, o = (j / 64) % 128, i = j % 64;
        float v = (o < 100 && i < 50) ? w3[(o * 50 + i) * 10 + k] : 0.f;
        wss[WK4 + j] = f2bf(v);
        return;
    }
    j -= 81920;
    if (j < 286720) {                          // wk5 [k][224][128]
        int k = j / 28672, o = (j / 128) % 224, i = j % 128;
        float v = (o < 200 && i < 100) ? w4[(o * 100 + i) * 10 + k] : 0.f;
        wss[WK5 + j] = f2bf(v);
    }
}

// ---- epilogue helper: shuffle-pool one acc, store bf16 short4s ------------
template<bool F32OUT>
__device__ __forceinline__ void pool_store(
    const f32x16& acc, const float* __restrict__ bias, int mbase,
    int half, bool act, int tp, short* __restrict__ orow,
    float* __restrict__ feats) {
#pragma unroll
    for (int q = 0; q < 4; ++q) {
        float ev[4];
#pragma unroll
        for (int rr = 0; rr < 4; ++rr) {
            float v = acc[q * 4 + rr];
            float v1 = __shfl_down(v, 1);
            float v2 = __shfl_down(v, 2);
            float m = fmaxf(fmaxf(v, v1), v2) + bias[mbase + q * 8 + 4 * half + rr];
            ev[rr] = m > 0.f ? m : __expf(m) - 1.f;
        }
        if (act) {
            int ob = mbase + q * 8 + 4 * half;
            if constexpr (F32OUT) {
#pragma unroll
                for (int rr = 0; rr < 4; ++rr)
                    if (ob + rr < 200) feats[(ob + rr) * 7 + tp] = ev[rr];
            } else {
                short4 hv;
                hv.x = f2bf(ev[0]); hv.y = f2bf(ev[1]);
                hv.z = f2bf(ev[2]); hv.w = f2bf(ev[3]);
                *(short4*)(orow + ob) = hv;
            }
        }
    }
}

// ---- K1: conv12 -> p1T[b][330][32]; grid 256*11, 192 thr (3 n-waves) ------
__global__ __launch_bounds__(192) void k_conv12(
    const short* __restrict__ wk, const float* __restrict__ bias,
    const float* __restrict__ x, short* __restrict__ outT) {
    __shared__ short xs[101 * 36];
    int b = blockIdx.x % 256, ch = blockIdx.x / 256;
    int u0 = ch * 90;
    int tid = threadIdx.x;
    const float* xb = x + b * 22000;
    for (int i = tid; i < 32 * 101; i += 192) {
        int c = i / 101, r = i - c * 101;
        short v = 0;
        if (c < 22) {
            int t = u0 + r; if (t > 999) t = 999;
            v = f2bf(xb[c * 1000 + t]);
        }
        xs[r * 36 + c] = v;
    }
    __syncthreads();

    int w = tid >> 6, lane = tid & 63, l31 = lane & 31, half = lane >> 5;
    f32x16 acc = {};
    const short* ab = wk + l31 * 32 + half * 8;
    const short* bb = xs + (w * 30 + l31) * 36 + half * 8;
#pragma unroll 2
    for (int k = 0; k < 10; ++k) {
#pragma unroll
        for (int kb = 0; kb < 2; ++kb)
            acc = __builtin_amdgcn_mfma_f32_32x32x16_bf16(
                *(const short8*)(ab + k * 1024 + kb * 16),
                *(const short8*)(bb + k * 36 + kb * 16), acc, 0, 0, 0);
    }
    bool act = ((l31 % 3) == 0) && (l31 < 30);
    int tp = ch * 30 + w * 10 + l31 / 3;
    pool_store<false>(acc, bias, 0, half, act, tp,
                      outT + ((size_t)b * 330 + tp) * 32, nullptr);
}

// ---- K2: conv3 -> p2T[b][107][64]; grid 256*4, 192 thr; 2 m-tiles/wave ----
__global__ __launch_bounds__(192) void k_conv3(
    const short* __restrict__ wk, const float* __restrict__ bias,
    const short* __restrict__ xT, short* __restrict__ outT) {
    __shared__ short xs[101 * 36];
    int b = blockIdx.x % 256, ch = blockIdx.x / 256;
    int u0 = ch * 90;
    int tid = threadIdx.x;
    const short8* src = (const short8*)(xT + (size_t)b * 330 * 32);
    for (int i = tid; i < 101 * 4; i += 192) {
        int r = i >> 2, vv = i & 3;
        int t = u0 + r; if (t > 329) t = 329;
        *(short8*)(xs + r * 36 + vv * 8) = src[t * 4 + vv];
    }
    __syncthreads();

    int w = tid >> 6, lane = tid & 63, l31 = lane & 31, half = lane >> 5;
    f32x16 acc0 = {}, acc1 = {};
    const short* ab = wk + l31 * 32 + half * 8;
    const short* bb = xs + (w * 30 + l31) * 36 + half * 8;
#pragma unroll 2
    for (int k = 0; k < 10; ++k) {
#pragma unroll
        for (int kb = 0; kb < 2; ++kb) {
            short8 bf = *(const short8*)(bb + k * 36 + kb * 16);
            const short* ap = ab + k * 2048 + kb * 16;
            acc0 = __builtin_amdgcn_mfma_f32_32x32x16_bf16(
                *(const short8*)(ap), bf, acc0, 0, 0, 0);
            acc1 = __builtin_amdgcn_mfma_f32_32x32x16_bf16(
                *(const short8*)(ap + 1024), bf, acc1, 0, 0, 0);
        }
    }
    int tp = ch * 30 + w * 10 + l31 / 3;
    bool act = ((l31 % 3) == 0) && (l31 < 30) && (tp < 107);
    short* orow = outT + ((size_t)b * 107 + (act ? tp : 0)) * 64;
    pool_store<false>(acc0, bias, 0, half, act, tp, orow, nullptr);
    pool_store<false>(acc1, bias, 32, half, act, tp, orow, nullptr);
}

// ---- K3: conv4 -> p3T[b][32][128]; grid 256, 512 thr; 2 m-tiles/wave ------
// 4 m-tiles total: pair = w&1 covers rows pair*64 .. pair*64+63; nt = w>>1.
__global__ __launch_bounds__(512) void k_conv4(
    const short* __restrict__ wk, const float* __restrict__ bias,
    const short* __restrict__ xT, short* __restrict__ outT) {
    __shared__ short xs[131 * 68];
    int b = blockIdx.x;
    int tid = threadIdx.x;
    const short8* src = (const short8*)(xT + (size_t)b * 107 * 64);
    for (int i = tid; i < 131 * 8; i += 512) {
        int r = i >> 3, vv = i & 7;
        int t = r < 107 ? r : 106;
        *(short8*)(xs + r * 68 + vv * 8) = src[t * 8 + vv];
    }
    __syncthreads();

    int w = tid >> 6, lane = tid & 63, l31 = lane & 31, half = lane >> 5;
    int pair = w & 1;               // m-rows pair*64 .. +63 (128 padded rows)
    int nt = w >> 1;                // 0..3
    f32x16 acc0 = {}, acc1 = {};
    const short* ab = wk + (size_t)(pair * 64 + l31) * 64 + half * 8;
    const short* bb = xs + (nt * 30 + l31) * 68 + half * 8;
#pragma unroll 2
    for (int k = 0; k < 10; ++k) {
#pragma unroll
        for (int kb = 0; kb < 4; ++kb) {
            short8 bf = *(const short8*)(bb + k * 68 + kb * 16);
            const short* ap = ab + (size_t)k * 8192 + kb * 16;
            acc0 = __builtin_amdgcn_mfma_f32_32x32x16_bf16(
                *(const short8*)(ap), bf, acc0, 0, 0, 0);
            acc1 = __builtin_amdgcn_mfma_f32_32x32x16_bf16(
                *(const short8*)(ap + 2048), bf, acc1, 0, 0, 0);
        }
    }
    int tp = nt * 10 + l31 / 3;
    bool act = ((l31 % 3) == 0) && (l31 < 30) && (tp < 32);
    short* orow = outT + ((size_t)b * 32 + (act ? tp : 0)) * 128;
    pool_store<false>(acc0, bias, pair * 64, half, act, tp, orow, nullptr);
    pool_store<false>(acc1, bias, pair * 64 + 32, half, act, tp, orow, nullptr);
}

// ---- K4: conv5 + routed head; grid 256, 448 thr (7 m-waves) ---------------
__global__ __launch_bounds__(448) void k_conv5h(
    const short* __restrict__ wk, const float* __restrict__ bias,
    const short* __restrict__ xT,
    const float* __restrict__ hW, const float* __restrict__ hB,
    const int* __restrict__ sid, float* __restrict__ out) {
    __shared__ short xs[41 * 132];
    __shared__ float feats[1400];
    int b = blockIdx.x;
    int tid = threadIdx.x;
    const short8* src = (const short8*)(xT + (size_t)b * 32 * 128);
    for (int i = tid; i < 41 * 16; i += 448) {
        int r = i >> 4, vv = i & 15;
        int t = r < 32 ? r : 31;
        *(short8*)(xs + r * 132 + vv * 8) = src[t * 16 + vv];
    }
    __syncthreads();

    int w = tid >> 6, lane = tid & 63, l31 = lane & 31, half = lane >> 5;
    f32x16 acc = {};
    const short* ab = wk + (size_t)(w * 32 + l31) * 128 + half * 8;
    const short* bb = xs + l31 * 132 + half * 8;
#pragma unroll 2
    for (int k = 0; k < 10; ++k) {
#pragma unroll
        for (int kb = 0; kb < 8; ++kb)
            acc = __builtin_amdgcn_mfma_f32_32x32x16_bf16(
                *(const short8*)(ab + (size_t)k * 28672 + kb * 16),
                *(const short8*)(bb + k * 132 + kb * 16), acc, 0, 0, 0);
    }
    int tp = l31 / 3;
    bool act = ((l31 % 3) == 0) && (l31 < 21);
    pool_store<true>(acc, bias, w * 32, half, act, tp, nullptr, feats);
    __syncthreads();

    if (w < 4) {
        int sidb = sid[b];
        const float* wrow = hW + (size_t)(sidb * 4 + w) * 1400;
        float a = 0.f;
        for (int f = lane; f < 1400; f += 64) a += wrow[f] * feats[f];
#pragma unroll
        for (int off = 32; off; off >>= 1) a += __shfl_down(a, off);
        if (lane == 0) out[b * 4 + w] = a + hB[sidb * 4 + w];
    }
}

extern "C" void kernel_launch(void* const* d_in, const int* in_sizes, int n_in,
                              void* d_out, int out_size, void* d_ws, size_t ws_size,
                              hipStream_t stream) {
    const float* x   = (const float*)d_in[0];
    const int*   sid = (const int*)d_in[1];
    const float* wt  = (const float*)d_in[2];
    const float* bt  = (const float*)d_in[3];
    const float* wsp = (const float*)d_in[4];
    const float* bsp = (const float*)d_in[5];
    const float* w2  = (const float*)d_in[6];
    const float* b2  = (const float*)d_in[7];
    const float* w3  = (const float*)d_in[8];
    const float* b3  = (const float*)d_in[9];
    const float* w4  = (const float*)d_in[10];
    const float* b4  = (const float*)d_in[11];
    const float* hW  = (const float*)d_in[12];
    const float* hB  = (const float*)d_in[13];
    float* out = (float*)d_out;
    float* wsf = (float*)d_ws;
    short* wss = (short*)d_ws + SHORT_BASE;

    k_prep2<<<1562, 256, 0, stream>>>(wt, bt, wsp, bsp, w2, b2, w3, b3, w4, b4,
                                      wsf, wss);
    k_conv12<<<256 * 11, 192, 0, stream>>>(wss + WK12, wsf + F_BC, x, wss + P1T);
    k_conv3<<<256 * 4, 192, 0, stream>>>(wss + WK3, wsf + F_B2, wss + P1T,
                                         wss + P2T);
    k_conv4<<<256, 512, 0, stream>>>(wss + WK4, wsf + F_B3, wss + P2T,
                                     wss + P3T);
    k_conv5h<<<256, 448, 0, stream>>>(wss + WK5, wsf + F_B4, wss + P3T,
                                      hW, hB, sid, out);
}